// Round 15
// baseline (698.211 us; speedup 1.0000x reference)
//
#include <hip/hip_runtime.h>
#include <hip/hip_bf16.h>
#include <math.h>

#define N_NODES 20000
#define N_EDGES 320000
#define D 128
#define DFF 512
#define DIN 16
#define NLAYER 4
#define SCALE 0.25f
#define KE1 288  // folded k for final L1 weights: 128 src + 128 dst + 32 rr

typedef __hip_bfloat16 bf16;
typedef __attribute__((ext_vector_type(8))) __bf16 bf16x8_t;
typedef __attribute__((ext_vector_type(4))) float f32x4;

// ---------------- input projection: h = x @ in_w + in_b (+ bf16 mirror) ----------------
__global__ void k_input_proj(const float* __restrict__ x, const float* __restrict__ in_w,
                             const float* __restrict__ in_b, float* __restrict__ h,
                             __bf16* __restrict__ h_bf) {
  int node = blockIdx.x;
  int j = threadIdx.x;  // 0..127
  __shared__ float xs[DIN];
  if (j < DIN) xs[j] = x[node * DIN + j];
  __syncthreads();
  float acc = in_b[j];
  for (int k = 0; k < DIN; ++k) acc = fmaf(xs[k], in_w[k * D + j], acc);
  h[(size_t)node * D + j] = acc;
  h_bf[(size_t)node * D + j] = (__bf16)acc;
}

// -------- edge prep: ew = sigmoid(sum(edge_feat)) (exact collapse) + degree count --------
__global__ void k_edge_prep(const float* __restrict__ ea, const float* __restrict__ w1,
                            const float* __restrict__ b1, const float* __restrict__ w2,
                            const float* __restrict__ b2, const int* __restrict__ dst,
                            float* __restrict__ ew, float* __restrict__ cnt) {
  __shared__ float rs[32], w1s[32], b1s[32];
  __shared__ float b2sum;
  int tid = threadIdx.x;
  if (tid < 32) {
    float s = 0.f;
    for (int j = 0; j < 64; ++j) s += w2[tid * 64 + j];
    rs[tid] = s;
    w1s[tid] = w1[tid];
    b1s[tid] = b1[tid];
  }
  if (tid == 0) {
    float s = 0.f;
    for (int j = 0; j < 64; ++j) s += b2[j];
    b2sum = s;
  }
  __syncthreads();
  int e = blockIdx.x * blockDim.x + tid;
  if (e >= N_EDGES) return;
  float a = ea[e];
  float s = b2sum;
  for (int i = 0; i < 32; ++i) {
    float t = fmaxf(fmaf(a, w1s[i], b1s[i]), 0.f);
    s = fmaf(t, rs[i], s);
  }
  ew[e] = 1.f / (1.f + expf(-s));
  atomicAdd(&cnt[dst[e]], 1.f);
}

// ---------------- CSR build: exclusive scan of cnt -> off (+ cursor copy) ----------------
__global__ __launch_bounds__(1024) void k_scan(const float* __restrict__ cnt,
                                               int* __restrict__ off,
                                               int* __restrict__ cursor) {
  __shared__ int ts[1024];
  int tid = threadIdx.x;
  const int per = (N_NODES + 1023) / 1024;  // 20
  int base = tid * per;
  int s = 0;
  for (int i = 0; i < per; ++i) {
    int idx = base + i;
    if (idx < N_NODES) s += (int)cnt[idx];
  }
  ts[tid] = s;
  __syncthreads();
  for (int st = 1; st < 1024; st <<= 1) {
    int v = (tid >= st) ? ts[tid - st] : 0;
    __syncthreads();
    ts[tid] += v;
    __syncthreads();
  }
  int run = (tid == 0) ? 0 : ts[tid - 1];
  for (int i = 0; i < per; ++i) {
    int idx = base + i;
    if (idx < N_NODES) {
      off[idx] = run;
      cursor[idx] = run;
      run += (int)cnt[idx];
    }
  }
  if (tid == 1023) off[N_NODES] = run;
}

// ---------------- CSR scatter: edges grouped by dst (src, dst, eid) ----------------
__global__ void k_scatter(const int* __restrict__ src, const int* __restrict__ dst,
                          int* __restrict__ cursor, int* __restrict__ csr_src,
                          int* __restrict__ csr_dst, int* __restrict__ csr_eid) {
  int e = blockIdx.x * blockDim.x + threadIdx.x;
  if (e >= N_EDGES) return;
  int d = dst[e];
  int pos = atomicAdd(&cursor[d], 1);
  csr_src[pos] = src[e];
  csr_dst[pos] = d;
  csr_eid[pos] = e;
}

// ---------------- weight prep: bf16 transpose [N][K] ----------------
__global__ void k_cvt_all(const float* __restrict__ Wq, const float* __restrict__ Wk,
                          const float* __restrict__ Wv, const float* __restrict__ ffw1,
                          const float* __restrict__ ffw2, const float* __restrict__ Wo,
                          const float* __restrict__ ecw2, const float* __restrict__ ppw2,
                          __bf16* __restrict__ wqkvT, __bf16* __restrict__ w1T,
                          __bf16* __restrict__ w2T, __bf16* __restrict__ woT,
                          __bf16* __restrict__ w2ET, __bf16* __restrict__ w2PT) {
  int t = blockIdx.x * 256 + threadIdx.x;
  if (t < 196608) {  // [L][3][128][128]: out[n][k] = W[l][k][n]
    int l = t / 49152, u = t % 49152;
    int m = u / 16384, v = u % 16384;
    int n = v / 128, k = v % 128;
    const float* W = (m == 0) ? Wq : (m == 1) ? Wk : Wv;
    wqkvT[t] = (__bf16)W[l * 16384 + k * 128 + n];
  } else if (t < 196608 + 262144) {  // ff w1 [L][128][512] -> [L][512][128]
    int u = t - 196608;
    int l = u / 65536, v = u % 65536;
    int n = v / 128, k = v % 128;
    w1T[u] = (__bf16)ffw1[l * 65536 + k * 512 + n];
  } else if (t < 458752 + 262144) {  // ff w2 [L][512][128] -> [L][128][512]
    int u = t - 458752;
    int l = u / 65536, v = u % 65536;
    int n = v / 512, k = v % 512;
    w2T[u] = (__bf16)ffw2[l * 65536 + k * 128 + n];
  } else if (t < 720896 + 65536) {  // Wo [L][128][128] -> [L][128][128]^T
    int u = t - 720896;
    int l = u / 16384, v = u % 16384;
    int n = v / 128, k = v % 128;
    woT[u] = (__bf16)Wo[l * 16384 + k * 128 + n];
  } else if (t < 786432 + 8192) {  // ec_w2 [128][64] -> [64][128]
    int u = t - 786432;
    int n = u / 128, k = u % 128;
    w2ET[u] = (__bf16)ecw2[k * 64 + n];
  } else if (t < 794624 + 8192) {
    int u = t - 794624;
    int n = u / 128, k = u % 128;
    w2PT[u] = (__bf16)ppw2[k * 64 + n];
  }
}

// ---------------- prep for final L1: fold edge_feat MLP into the weights ----------------
__global__ void k_prep(const float* __restrict__ ec_w1, const float* __restrict__ ec_b1,
                       const float* __restrict__ pp_w1, const float* __restrict__ pp_b1,
                       const float* __restrict__ ee_w2, const float* __restrict__ ee_b2,
                       __bf16* __restrict__ w1ET, __bf16* __restrict__ w1PT,
                       float* __restrict__ b1Ep, float* __restrict__ b1Pp) {
  int tid = threadIdx.x;  // 0..255
  int p = tid >> 7, n = tid & 127;
  const float* w1 = p ? pp_w1 : ec_w1;
  const float* bb = p ? pp_b1 : ec_b1;
  __bf16* wT = p ? w1PT : w1ET;
  float* bo = p ? b1Pp : b1Ep;
  for (int k = 0; k < 256; ++k) wT[n * KE1 + k] = (__bf16)w1[k * 128 + n];
  for (int i = 0; i < 32; ++i) {
    float m = 0.f;
    for (int j = 0; j < 64; ++j) m = fmaf(ee_w2[i * 64 + j], w1[(256 + j) * 128 + n], m);
    wT[n * KE1 + 256 + i] = (__bf16)m;
  }
  float b = bb[n];
  for (int j = 0; j < 64; ++j) b = fmaf(ee_b2[j], w1[(256 + j) * 128 + n], b);
  bo[n] = b;
}

// ---------- QKV layer 0: col-split, 16 nodes/block, 4 waves (wave = 6 nb of 24) ----------
__global__ __launch_bounds__(256) void k_qkv(const __bf16* __restrict__ h_bf,
                                             const __bf16* __restrict__ wT,
                                             __bf16* __restrict__ Q, __bf16* __restrict__ K,
                                             __bf16* __restrict__ V) {
  int tid = threadIdx.x, wv = tid >> 6, lane = tid & 63;
  int lr = lane & 15, lk = (lane >> 4) * 8, g4 = (lane >> 4) * 4;
  int n0 = blockIdx.x * 16;
  const __bf16* hp = h_bf + (size_t)(n0 + lr) * D;
  f32x4 acc[6];
#pragma unroll
  for (int j = 0; j < 6; ++j) acc[j] = (f32x4){0.f, 0.f, 0.f, 0.f};
#pragma unroll
  for (int ks = 0; ks < 4; ++ks) {
    bf16x8_t aF = *(const bf16x8_t*)&hp[ks * 32 + lk];
#pragma unroll
    for (int j = 0; j < 6; ++j) {
      int nb = wv * 6 + j;
      bf16x8_t bF = *(const bf16x8_t*)&wT[(nb * 16 + lr) * 128 + ks * 32 + lk];
      acc[j] = __builtin_amdgcn_mfma_f32_16x16x32_bf16(aF, bF, acc[j], 0, 0, 0);
    }
  }
#pragma unroll
  for (int j = 0; j < 6; ++j) {
    int nb = wv * 6 + j;
    int m = nb >> 3;
    __bf16* out = (m == 0) ? Q : (m == 1) ? K : V;
#pragma unroll
    for (int r = 0; r < 4; ++r)
      out[(size_t)(n0 + g4 + r) * D + (nb & 7) * 16 + lr] = (__bf16)acc[j][r];
  }
}

// ---------------- edge attention: scalar score sums per (dst, head), atomics ----------
__global__ void k_edge_attn(const int* __restrict__ src, const int* __restrict__ dst,
                            const float* __restrict__ ew, const __bf16* __restrict__ Q,
                            const __bf16* __restrict__ K, float* __restrict__ sc) {
  int t = blockIdx.x * blockDim.x + threadIdx.x;
  if (t >= N_EDGES * 8) return;
  int e = t >> 3, hd = t & 7;
  int s = src[e], d = dst[e];
  const __bf16* q = Q + (size_t)s * D + hd * 16;
  const __bf16* k = K + (size_t)d * D + hd * 16;
  bf16x8_t q0 = *(const bf16x8_t*)q, q1 = *(const bf16x8_t*)(q + 8);
  bf16x8_t k0 = *(const bf16x8_t*)k, k1 = *(const bf16x8_t*)(k + 8);
  float p = 0.f;
#pragma unroll
  for (int i = 0; i < 8; ++i) p = fmaf((float)q0[i], (float)k0[i], p);
#pragma unroll
  for (int i = 0; i < 8; ++i) p = fmaf((float)q1[i], (float)k1[i], p);
  atomicAdd(&sc[d * 8 + hd], p * SCALE * ew[e]);
}

// ---- fused node kernel, col-split: 16 nodes/block, 4 waves each owning a col slice ----
// Zeroes its sc slots after reading (saves per-layer memset). Last layer
// (wqkvT_next==nullptr): computes Ps/Pd for the final MLPs instead of QKV.
__global__ __launch_bounds__(256) void k_node(
    float* __restrict__ sc, const float* __restrict__ cnt, const __bf16* __restrict__ Vin,
    float* __restrict__ h, __bf16* __restrict__ h_bf, const __bf16* __restrict__ woT,
    const float* __restrict__ Wo_b, const float* __restrict__ ln1_s,
    const float* __restrict__ ln1_b, const __bf16* __restrict__ w1T,
    const __bf16* __restrict__ w2T, const float* __restrict__ b1,
    const float* __restrict__ b2, const float* __restrict__ ln2_s,
    const float* __restrict__ ln2_b, const __bf16* __restrict__ wqkvT_next,
    __bf16* __restrict__ Q, __bf16* __restrict__ K, __bf16* __restrict__ Vout,
    const __bf16* __restrict__ w1ET, const __bf16* __restrict__ w1PT,
    __bf16* __restrict__ PsE, __bf16* __restrict__ PdE, __bf16* __restrict__ PsP,
    __bf16* __restrict__ PdP) {
  __shared__ __bf16 z0[16][136];
  __shared__ __bf16 z1[16][520];
  __shared__ float lnb[4][16][2];
  int tid = threadIdx.x, wv = tid >> 6, lane = tid & 63;
  int lr = lane & 15, lk = (lane >> 4) * 8, g4 = (lane >> 4) * 4;
  int n0 = blockIdx.x * 16;
  int nd = n0 + lr;  // exact: 1250*16 == N_NODES

  // ---- phase 1: att-out GEMM, wave cols [wv*32, wv*32+32) ----
  float inv = 1.f / fmaxf(cnt[nd], 1.f);
  float scs[8];
#pragma unroll
  for (int i = 0; i < 8; ++i) scs[i] = sc[nd * 8 + i] * inv;
  f32x4 acc[2];
#pragma unroll
  for (int j = 0; j < 2; ++j) {
    float bv = Wo_b[(wv * 2 + j) * 16 + lr];
    acc[j] = (f32x4){bv, bv, bv, bv};
  }
#pragma unroll
  for (int ks = 0; ks < 4; ++ks) {
    bf16x8_t v8 = *(const bf16x8_t*)&Vin[(size_t)nd * D + ks * 32 + lk];
    float m = scs[(ks * 32 + lk) >> 4];
    bf16x8_t aF;
#pragma unroll
    for (int i = 0; i < 8; ++i) aF[i] = (__bf16)((float)v8[i] * m);
#pragma unroll
    for (int j = 0; j < 2; ++j) {
      bf16x8_t bF = *(const bf16x8_t*)&woT[((wv * 2 + j) * 16 + lr) * 128 + ks * 32 + lk];
      acc[j] = __builtin_amdgcn_mfma_f32_16x16x32_bf16(aF, bF, acc[j], 0, 0, 0);
    }
  }
  // residual + LN1 partials
  float y[2][4];
#pragma unroll
  for (int j = 0; j < 2; ++j)
#pragma unroll
    for (int r = 0; r < 4; ++r)
      y[j][r] = h[(size_t)(n0 + g4 + r) * D + (wv * 2 + j) * 16 + lr] + acc[j][r];
  float s_[4], q_[4];
#pragma unroll
  for (int r = 0; r < 4; ++r) {
    float a0 = y[0][r], a1 = y[1][r];
    float s = a0 + a1, q = fmaf(a0, a0, a1 * a1);
    s += __shfl_xor(s, 1); s += __shfl_xor(s, 2); s += __shfl_xor(s, 4); s += __shfl_xor(s, 8);
    q += __shfl_xor(q, 1); q += __shfl_xor(q, 2); q += __shfl_xor(q, 4); q += __shfl_xor(q, 8);
    s_[r] = s; q_[r] = q;
  }
  if (lr == 0) {
#pragma unroll
    for (int r = 0; r < 4; ++r) {
      lnb[wv][g4 + r][0] = s_[r];
      lnb[wv][g4 + r][1] = q_[r];
    }
  }
  __syncthreads();  // A: lnb1 ready; all waves past sc reads
  if (tid < 128) sc[n0 * 8 + tid] = 0.f;  // zero for next layer
  float mean[4], rstd[4];
#pragma unroll
  for (int r = 0; r < 4; ++r) {
    float sm = 0.f, sq = 0.f;
#pragma unroll
    for (int w2i = 0; w2i < 4; ++w2i) {
      sm += lnb[w2i][g4 + r][0];
      sq += lnb[w2i][g4 + r][1];
    }
    float mu = sm * (1.f / 128.f);
    mean[r] = mu;
    rstd[r] = rsqrtf(sq * (1.f / 128.f) - mu * mu + 1e-5f);
  }
#pragma unroll
  for (int j = 0; j < 2; ++j) {
    int col = (wv * 2 + j) * 16 + lr;
    float lsv = ln1_s[col], lbv = ln1_b[col];
#pragma unroll
    for (int r = 0; r < 4; ++r) {
      y[j][r] = (y[j][r] - mean[r]) * rstd[r] * lsv + lbv;
      z0[g4 + r][col] = (__bf16)y[j][r];
    }
  }
  __syncthreads();  // B: z0 ready

  // ---- FF1: wave cols [wv*128, wv*128+128) of 512 ----
  f32x4 a1[8];
#pragma unroll
  for (int j = 0; j < 8; ++j) {
    float bv = b1[(wv * 8 + j) * 16 + lr];
    a1[j] = (f32x4){bv, bv, bv, bv};
  }
#pragma unroll
  for (int ks = 0; ks < 4; ++ks) {
    bf16x8_t aF = *(const bf16x8_t*)&z0[lr][ks * 32 + lk];
#pragma unroll
    for (int j = 0; j < 8; ++j) {
      bf16x8_t bF = *(const bf16x8_t*)&w1T[((wv * 8 + j) * 16 + lr) * 128 + ks * 32 + lk];
      a1[j] = __builtin_amdgcn_mfma_f32_16x16x32_bf16(aF, bF, a1[j], 0, 0, 0);
    }
  }
#pragma unroll
  for (int j = 0; j < 8; ++j)
#pragma unroll
    for (int r = 0; r < 4; ++r)
      z1[g4 + r][(wv * 8 + j) * 16 + lr] = (__bf16)fmaxf(a1[j][r], 0.f);
  __syncthreads();  // C: z1 ready, z0 free

  // ---- FF2: wave cols [wv*32, wv*32+32), k = 512 ----
  f32x4 a2[2];
#pragma unroll
  for (int j = 0; j < 2; ++j) {
    float bv = b2[(wv * 2 + j) * 16 + lr];
    a2[j] = (f32x4){bv, bv, bv, bv};
  }
#pragma unroll
  for (int ks = 0; ks < 16; ++ks) {
    bf16x8_t aF = *(const bf16x8_t*)&z1[lr][ks * 32 + lk];
#pragma unroll
    for (int j = 0; j < 2; ++j) {
      bf16x8_t bF = *(const bf16x8_t*)&w2T[((wv * 2 + j) * 16 + lr) * 512 + ks * 32 + lk];
      a2[j] = __builtin_amdgcn_mfma_f32_16x16x32_bf16(aF, bF, a2[j], 0, 0, 0);
    }
  }
  // residual (post-LN1 y) + LN2
#pragma unroll
  for (int j = 0; j < 2; ++j)
#pragma unroll
    for (int r = 0; r < 4; ++r) y[j][r] += a2[j][r];
#pragma unroll
  for (int r = 0; r < 4; ++r) {
    float a0 = y[0][r], a1v = y[1][r];
    float s = a0 + a1v, q = fmaf(a0, a0, a1v * a1v);
    s += __shfl_xor(s, 1); s += __shfl_xor(s, 2); s += __shfl_xor(s, 4); s += __shfl_xor(s, 8);
    q += __shfl_xor(q, 1); q += __shfl_xor(q, 2); q += __shfl_xor(q, 4); q += __shfl_xor(q, 8);
    s_[r] = s; q_[r] = q;
  }
  if (lr == 0) {
#pragma unroll
    for (int r = 0; r < 4; ++r) {
      lnb[wv][g4 + r][0] = s_[r];
      lnb[wv][g4 + r][1] = q_[r];
    }
  }
  __syncthreads();  // D: lnb2 ready
#pragma unroll
  for (int r = 0; r < 4; ++r) {
    float sm = 0.f, sq = 0.f;
#pragma unroll
    for (int w2i = 0; w2i < 4; ++w2i) {
      sm += lnb[w2i][g4 + r][0];
      sq += lnb[w2i][g4 + r][1];
    }
    float mu = sm * (1.f / 128.f);
    mean[r] = mu;
    rstd[r] = rsqrtf(sq * (1.f / 128.f) - mu * mu + 1e-5f);
  }
#pragma unroll
  for (int j = 0; j < 2; ++j) {
    int col = (wv * 2 + j) * 16 + lr;
    float lsv = ln2_s[col], lbv = ln2_b[col];
#pragma unroll
    for (int r = 0; r < 4; ++r) {
      float yv = (y[j][r] - mean[r]) * rstd[r] * lsv + lbv;
      y[j][r] = yv;
      h[(size_t)(n0 + g4 + r) * D + col] = yv;
      h_bf[(size_t)(n0 + g4 + r) * D + col] = (__bf16)yv;
    }
  }

  // ---- restage y2 into z0 for the tail GEMM (QKV or final-P) ----
#pragma unroll
  for (int j = 0; j < 2; ++j)
#pragma unroll
    for (int r = 0; r < 4; ++r)
      z0[g4 + r][(wv * 2 + j) * 16 + lr] = (__bf16)y[j][r];
  __syncthreads();  // E: z0 = y2 ready

  if (wqkvT_next) {
    // ---- next-layer QKV, col-split 6 nb/wave ----
    f32x4 aq[6];
#pragma unroll
    for (int j = 0; j < 6; ++j) aq[j] = (f32x4){0.f, 0.f, 0.f, 0.f};
#pragma unroll
    for (int ks = 0; ks < 4; ++ks) {
      bf16x8_t aF = *(const bf16x8_t*)&z0[lr][ks * 32 + lk];
#pragma unroll
      for (int j = 0; j < 6; ++j) {
        int nb = wv * 6 + j;
        bf16x8_t bF = *(const bf16x8_t*)&wqkvT_next[(nb * 16 + lr) * 128 + ks * 32 + lk];
        aq[j] = __builtin_amdgcn_mfma_f32_16x16x32_bf16(aF, bF, aq[j], 0, 0, 0);
      }
    }
#pragma unroll
    for (int j = 0; j < 6; ++j) {
      int nb = wv * 6 + j;
      int m = nb >> 3;
      __bf16* out = (m == 0) ? Q : (m == 1) ? K : Vout;
#pragma unroll
      for (int r = 0; r < 4; ++r)
        out[(size_t)(n0 + g4 + r) * D + (nb & 7) * 16 + lr] = (__bf16)aq[j][r];
    }
  } else {
    // ---- final-P: wave wv -> {PsE, PdE, PsP, PdP}, own 16 rows (safe: Vin reads done) ----
    const __bf16* wsrc = (wv & 2) ? w1PT : w1ET;
    int koff = (wv & 1) ? 128 : 0;
    __bf16* outP = (wv == 0) ? PsE : (wv == 1) ? PdE : (wv == 2) ? PsP : PdP;
    f32x4 ap[8];
#pragma unroll
    for (int nb = 0; nb < 8; ++nb) ap[nb] = (f32x4){0.f, 0.f, 0.f, 0.f};
#pragma unroll
    for (int ks = 0; ks < 4; ++ks) {
      bf16x8_t aF = *(const bf16x8_t*)&z0[lr][ks * 32 + lk];
#pragma unroll
      for (int nb = 0; nb < 8; ++nb) {
        bf16x8_t bF = *(const bf16x8_t*)&wsrc[(nb * 16 + lr) * KE1 + koff + ks * 32 + lk];
        ap[nb] = __builtin_amdgcn_mfma_f32_16x16x32_bf16(aF, bF, ap[nb], 0, 0, 0);
      }
    }
#pragma unroll
    for (int nb = 0; nb < 8; ++nb)
#pragma unroll
      for (int r = 0; r < 4; ++r)
        outP[(size_t)(n0 + g4 + r) * D + nb * 16 + lr] = (__bf16)ap[nb][r];
  }
}

// ---------------- final edge MLPs over dst-sorted CSR edges ----------------
// 256 threads = 4 waves: wave = {path p = wv&1, tile t = wv>>1}. 32 CSR positions/block.
// dst-sorted order makes Pd gathers L2-resident; outputs scattered via eid.
__global__ __launch_bounds__(256) void k_final(
    const int* __restrict__ csr_src, const int* __restrict__ csr_dst,
    const int* __restrict__ csr_eid, const float* __restrict__ ea,
    const float* __restrict__ ee_w1, const float* __restrict__ ee_b1,
    const __bf16* __restrict__ w1ET, const __bf16* __restrict__ w1PT,
    const __bf16* __restrict__ w2ET, const __bf16* __restrict__ w2PT,
    const float* __restrict__ b1Ep, const float* __restrict__ b1Pp,
    const __bf16* __restrict__ PsE, const __bf16* __restrict__ PdE,
    const __bf16* __restrict__ PsP, const __bf16* __restrict__ PdP,
    const float* __restrict__ ec_b2, const float* __restrict__ ec_w3,
    const float* __restrict__ ec_b3, const float* __restrict__ pp_b2,
    const float* __restrict__ pp_w3, const float* __restrict__ pp_b3,
    float* __restrict__ out_logits, float* __restrict__ out_params) {
  __shared__ __bf16 z1[2][32][136];
  __shared__ __bf16 zf[4][16][136];
  int tid = threadIdx.x, wv = tid >> 6, lane = tid & 63;
  int lr = lane & 15, lk = (lane >> 4) * 8, g4 = (lane >> 4) * 4;
  int p = wv & 1, m0 = (wv >> 1) * 16;
  int e0 = blockIdx.x * 32;
  int e = e0 + m0 + lr;  // CSR position
  int eid = csr_eid[e];
  float av = ea[eid];
  bf16x8_t aR;
#pragma unroll
  for (int i = 0; i < 8; ++i)
    aR[i] = (__bf16)fmaxf(fmaf(av, ee_w1[lk + i], ee_b1[lk + i]), 0.f);

  const __bf16* w1x = p ? w1PT : w1ET;
  const float* b1x = p ? b1Pp : b1Ep;
  const __bf16* w2x = p ? w2PT : w2ET;
  const float* b2x = p ? pp_b2 : ec_b2;

  // ---- feat part of L1: K=32 MFMA (bias-initialized), D-layout -> zf ----
  f32x4 acc[8];
#pragma unroll
  for (int nb = 0; nb < 8; ++nb) {
    float bv = b1x[nb * 16 + lr];
    acc[nb] = (f32x4){bv, bv, bv, bv};
  }
#pragma unroll
  for (int nb = 0; nb < 8; ++nb) {
    bf16x8_t bF = *(const bf16x8_t*)&w1x[(nb * 16 + lr) * KE1 + 256 + lk];
    acc[nb] = __builtin_amdgcn_mfma_f32_16x16x32_bf16(aR, bF, acc[nb], 0, 0, 0);
  }
#pragma unroll
  for (int nb = 0; nb < 8; ++nb)
#pragma unroll
    for (int r = 0; r < 4; ++r) zf[wv][g4 + r][nb * 16 + lr] = (__bf16)acc[nb][r];

  // ---- z1 assembly: lane = em*4 + c4; z1 = relu(Ps[src] + Pd[dst] + zf) ----
  {
    int em = lane >> 2, c4 = lane & 3;
    int ee = e0 + m0 + em;
    const __bf16* Ps = p ? PsP : PsE;
    const __bf16* Pd = p ? PdP : PdE;
    const __bf16* psrow = Ps + (size_t)csr_src[ee] * D + c4 * 32;
    const __bf16* pdrow = Pd + (size_t)csr_dst[ee] * D + c4 * 32;
#pragma unroll
    for (int ch = 0; ch < 4; ++ch) {
      bf16x8_t a = *(const bf16x8_t*)&psrow[ch * 8];
      bf16x8_t b = *(const bf16x8_t*)&pdrow[ch * 8];
      bf16x8_t f = *(const bf16x8_t*)&zf[wv][em][c4 * 32 + ch * 8];
      bf16x8_t o;
#pragma unroll
      for (int i = 0; i < 8; ++i)
        o[i] = (__bf16)fmaxf((float)a[i] + (float)b[i] + (float)f[i], 0.f);
      *(bf16x8_t*)&z1[p][m0 + em][c4 * 32 + ch * 8] = o;
    }
  }
  // wave-local rows -> no barrier anywhere

  // ---- layer 2: k=128, 64 cols ----
  f32x4 acc2[4];
#pragma unroll
  for (int nb = 0; nb < 4; ++nb) {
    float bv = b2x[nb * 16 + lr];
    acc2[nb] = (f32x4){bv, bv, bv, bv};
  }
#pragma unroll
  for (int ks = 0; ks < 4; ++ks) {
    bf16x8_t aF = *(const bf16x8_t*)&z1[p][m0 + lr][ks * 32 + lk];
#pragma unroll
    for (int nb = 0; nb < 4; ++nb) {
      bf16x8_t bF = *(const bf16x8_t*)&w2x[(nb * 16 + lr) * 128 + ks * 32 + lk];
      acc2[nb] = __builtin_amdgcn_mfma_f32_16x16x32_bf16(aF, bF, acc2[nb], 0, 0, 0);
    }
  }

  // ---- layer 3 (scattered writes via eid) ----
  if (p == 0) {
    float w3v[4];
#pragma unroll
    for (int nb = 0; nb < 4; ++nb) w3v[nb] = ec_w3[nb * 16 + lr];
    float b3 = ec_b3[0];
#pragma unroll
    for (int r = 0; r < 4; ++r) {
      float s = 0.f;
#pragma unroll
      for (int nb = 0; nb < 4; ++nb) s = fmaf(fmaxf(acc2[nb][r], 0.f), w3v[nb], s);
      s += __shfl_xor(s, 1);
      s += __shfl_xor(s, 2);
      s += __shfl_xor(s, 4);
      s += __shfl_xor(s, 8);
      if (lr == 0) out_logits[csr_eid[e0 + m0 + g4 + r]] = s + b3;
    }
  } else {
    float wp[4][4];
#pragma unroll
    for (int nb = 0; nb < 4; ++nb)
#pragma unroll
      for (int c = 0; c < 4; ++c) wp[nb][c] = pp_w3[(nb * 16 + lr) * 4 + c];
#pragma unroll
    for (int c = 0; c < 4; ++c) {
      float b3 = pp_b3[c];
#pragma unroll
      for (int r = 0; r < 4; ++r) {
        float s = 0.f;
#pragma unroll
        for (int nb = 0; nb < 4; ++nb) s = fmaf(fmaxf(acc2[nb][r], 0.f), wp[nb][c], s);
        s += __shfl_xor(s, 1);
        s += __shfl_xor(s, 2);
        s += __shfl_xor(s, 4);
        s += __shfl_xor(s, 8);
        if (lr == 0) {
          float xx = s + b3;
          float sp = fmaxf(xx, 0.f) + log1pf(expf(-fabsf(xx)));
          out_params[(size_t)csr_eid[e0 + m0 + g4 + r] * 4 + c] = sp + 1e-6f;
        }
      }
    }
  }
}

extern "C" void kernel_launch(void* const* d_in, const int* in_sizes, int n_in,
                              void* d_out, int out_size, void* d_ws, size_t ws_size,
                              hipStream_t stream) {
  const float* x = (const float*)d_in[0];
  const int* eidx = (const int*)d_in[1];
  const float* eattr = (const float*)d_in[2];
  const float* in_w = (const float*)d_in[3];
  const float* in_b = (const float*)d_in[4];
  const float* ee_w1 = (const float*)d_in[5];
  const float* ee_b1 = (const float*)d_in[6];
  const float* ee_w2 = (const float*)d_in[7];
  const float* ee_b2 = (const float*)d_in[8];
  const float* Wq = (const float*)d_in[9];
  const float* Wk = (const float*)d_in[10];
  const float* Wv = (const float*)d_in[11];
  const float* Wo = (const float*)d_in[12];
  const float* Wo_b = (const float*)d_in[13];
  const float* ff_w1 = (const float*)d_in[14];
  const float* ff_b1 = (const float*)d_in[15];
  const float* ff_w2 = (const float*)d_in[16];
  const float* ff_b2 = (const float*)d_in[17];
  const float* ln1_s = (const float*)d_in[18];
  const float* ln1_b = (const float*)d_in[19];
  const float* ln2_s = (const float*)d_in[20];
  const float* ln2_b = (const float*)d_in[21];
  const float* ec_w1 = (const float*)d_in[22];
  const float* ec_b1 = (const float*)d_in[23];
  const float* ec_w2 = (const float*)d_in[24];
  const float* ec_b2 = (const float*)d_in[25];
  const float* ec_w3 = (const float*)d_in[26];
  const float* ec_b3 = (const float*)d_in[27];
  const float* pp_w1 = (const float*)d_in[28];
  const float* pp_b1 = (const float*)d_in[29];
  const float* pp_w2 = (const float*)d_in[30];
  const float* pp_b2 = (const float*)d_in[31];
  const float* pp_w3 = (const float*)d_in[32];
  const float* pp_b3 = (const float*)d_in[33];

  const int* src = eidx;
  const int* dst = eidx + N_EDGES;

  // Workspace layout (43.6 MB, 16B-aligned)
  char* wsb = (char*)d_ws;
  float* sc = (float*)wsb;                     //    640,000
  float* cnt = (float*)(wsb + 640000);         //     80,000
  float* h = (float*)(wsb + 720000);           // 10,240,000
  __bf16* h_bf = (__bf16*)(wsb + 10960000);    //  5,120,000
  __bf16* Q = (__bf16*)(wsb + 16080000);       //  5,120,000
  __bf16* Kb = (__bf16*)(wsb + 21200000);      //  5,120,000
  __bf16* V0 = (__bf16*)(wsb + 26320000);      //  5,120,000
  __bf16* V1 = (__bf16*)(wsb + 31440000);      //  5,120,000
  float* ew = (float*)(wsb + 36560000);        //  1,280,000
  __bf16* wqkvT = (__bf16*)(wsb + 37840000);   //    393,216
  __bf16* w1T = (__bf16*)(wsb + 38233216);     //    524,288
  __bf16* w2T = (__bf16*)(wsb + 38757504);     //    524,288
  __bf16* woT = (__bf16*)(wsb + 39281792);     //    131,072
  __bf16* w1ET = (__bf16*)(wsb + 39412864);    //     73,728
  __bf16* w1PT = (__bf16*)(wsb + 39486592);    //     73,728
  __bf16* w2ET = (__bf16*)(wsb + 39560320);    //     16,384
  __bf16* w2PT = (__bf16*)(wsb + 39576704);    //     16,384
  float* b1Ep = (float*)(wsb + 39593088);      //        512
  float* b1Pp = (float*)(wsb + 39593600);      //        512
  int* off = (int*)(wsb + 39594112);           //     80,016 (20001 ints, padded)
  int* cursor = (int*)(wsb + 39674128);        //     80,000
  int* csr_src = (int*)(wsb + 39754128);       //  1,280,000
  int* csr_dst = (int*)(wsb + 41034128);       //  1,280,000
  int* csr_eid = (int*)(wsb + 42314128);       //  1,280,000 -> 43,594,128 total

  hipMemsetAsync(cnt, 0, N_NODES * sizeof(float), stream);
  hipMemsetAsync(sc, 0, N_NODES * 8 * sizeof(float), stream);
  k_input_proj<<<N_NODES, D, 0, stream>>>(x, in_w, in_b, h, h_bf);
  k_edge_prep<<<(N_EDGES + 255) / 256, 256, 0, stream>>>(eattr, ee_w1, ee_b1, ee_w2, ee_b2,
                                                         dst, ew, cnt);
  k_scan<<<1, 1024, 0, stream>>>(cnt, off, cursor);
  k_scatter<<<(N_EDGES + 255) / 256, 256, 0, stream>>>(src, dst, cursor, csr_src, csr_dst,
                                                       csr_eid);
  k_cvt_all<<<(802816 + 255) / 256, 256, 0, stream>>>(Wq, Wk, Wv, ff_w1, ff_w2, Wo, ec_w2,
                                                      pp_w2, wqkvT, w1T, w2T, woT, w2ET, w2PT);
  k_prep<<<1, 256, 0, stream>>>(ec_w1, ec_b1, pp_w1, pp_b1, ee_w2, ee_b2, w1ET, w1PT, b1Ep,
                                b1Pp);

  // Q/Kb/V0/V1 double duty: attention buffers during layers; Ps/Pd after the last k_node.
  __bf16* PsE = Q;
  __bf16* PdE = Kb;
  __bf16* PsP = V0;
  __bf16* PdP = V1;

  int nblk = N_NODES / 16;  // 1250, exact
  k_qkv<<<nblk, 256, 0, stream>>>(h_bf, wqkvT, Q, Kb, V0);
  for (int l = 0; l < NLAYER; ++l) {
    __bf16* Vin = (l & 1) ? V1 : V0;
    __bf16* Vout = (l & 1) ? V0 : V1;
    k_edge_attn<<<(N_EDGES * 8 + 255) / 256, 256, 0, stream>>>(src, dst, ew, Q, Kb, sc);
    k_node<<<nblk, 256, 0, stream>>>(
        sc, cnt, Vin, h, h_bf, woT + (size_t)l * 16384, Wo_b + l * D, ln1_s + l * D,
        ln1_b + l * D, w1T + (size_t)l * 65536, w2T + (size_t)l * 65536, ff_b1 + l * DFF,
        ff_b2 + l * D, ln2_s + l * D, ln2_b + l * D,
        (l < NLAYER - 1) ? (wqkvT + (size_t)(l + 1) * 49152) : (const __bf16*)nullptr, Q, Kb,
        Vout, w1ET, w1PT, PsE, PdE, PsP, PdP);
  }

  float* out_logits = (float*)d_out;
  float* out_params = out_logits + N_EDGES;
  k_final<<<N_EDGES / 32, 256, 0, stream>>>(csr_src, csr_dst, csr_eid, eattr, ee_w1, ee_b1,
                                            w1ET, w1PT, w2ET, w2PT, b1Ep, b1Pp, PsE, PdE,
                                            PsP, PdP, ec_b2, ec_w3, ec_b3, pp_b2, pp_w3,
                                            pp_b3, out_logits, out_params);
}

// Round 16
// 599.874 us; speedup vs baseline: 1.1639x; 1.1639x over previous
//
#include <hip/hip_runtime.h>
#include <hip/hip_bf16.h>
#include <math.h>

#define N_NODES 20000
#define N_EDGES 320000
#define D 128
#define DFF 512
#define DIN 16
#define NLAYER 4
#define SCALE 0.25f
#define KE1 288  // folded k for final L1 weights: 128 src + 128 dst + 32 rr

typedef __hip_bfloat16 bf16;
typedef __attribute__((ext_vector_type(8))) __bf16 bf16x8_t;
typedef __attribute__((ext_vector_type(4))) float f32x4;

// ---------------- input projection: h = x @ in_w + in_b (+ bf16 mirror) ----------------
__global__ void k_input_proj(const float* __restrict__ x, const float* __restrict__ in_w,
                             const float* __restrict__ in_b, float* __restrict__ h,
                             __bf16* __restrict__ h_bf) {
  int node = blockIdx.x;
  int j = threadIdx.x;  // 0..127
  __shared__ float xs[DIN];
  if (j < DIN) xs[j] = x[node * DIN + j];
  __syncthreads();
  float acc = in_b[j];
  for (int k = 0; k < DIN; ++k) acc = fmaf(xs[k], in_w[k * D + j], acc);
  h[(size_t)node * D + j] = acc;
  h_bf[(size_t)node * D + j] = (__bf16)acc;
}

// -------- edge prep: ew = sigmoid(sum(edge_feat)) (exact collapse) + degree count --------
__global__ void k_edge_prep(const float* __restrict__ ea, const float* __restrict__ w1,
                            const float* __restrict__ b1, const float* __restrict__ w2,
                            const float* __restrict__ b2, const int* __restrict__ dst,
                            float* __restrict__ ew, float* __restrict__ cnt) {
  __shared__ float rs[32], w1s[32], b1s[32];
  __shared__ float b2sum;
  int tid = threadIdx.x;
  if (tid < 32) {
    float s = 0.f;
    for (int j = 0; j < 64; ++j) s += w2[tid * 64 + j];
    rs[tid] = s;
    w1s[tid] = w1[tid];
    b1s[tid] = b1[tid];
  }
  if (tid == 0) {
    float s = 0.f;
    for (int j = 0; j < 64; ++j) s += b2[j];
    b2sum = s;
  }
  __syncthreads();
  int e = blockIdx.x * blockDim.x + tid;
  if (e >= N_EDGES) return;
  float a = ea[e];
  float s = b2sum;
  for (int i = 0; i < 32; ++i) {
    float t = fmaxf(fmaf(a, w1s[i], b1s[i]), 0.f);
    s = fmaf(t, rs[i], s);
  }
  ew[e] = 1.f / (1.f + expf(-s));
  atomicAdd(&cnt[dst[e]], 1.f);
}

// ---------------- weight prep: bf16 transpose [N][K] ----------------
__global__ void k_cvt_all(const float* __restrict__ Wq, const float* __restrict__ Wk,
                          const float* __restrict__ Wv, const float* __restrict__ ffw1,
                          const float* __restrict__ ffw2, const float* __restrict__ Wo,
                          const float* __restrict__ ecw2, const float* __restrict__ ppw2,
                          __bf16* __restrict__ wqkvT, __bf16* __restrict__ w1T,
                          __bf16* __restrict__ w2T, __bf16* __restrict__ woT,
                          __bf16* __restrict__ w2ET, __bf16* __restrict__ w2PT) {
  int t = blockIdx.x * 256 + threadIdx.x;
  if (t < 196608) {  // [L][3][128][128]: out[n][k] = W[l][k][n]
    int l = t / 49152, u = t % 49152;
    int m = u / 16384, v = u % 16384;
    int n = v / 128, k = v % 128;
    const float* W = (m == 0) ? Wq : (m == 1) ? Wk : Wv;
    wqkvT[t] = (__bf16)W[l * 16384 + k * 128 + n];
  } else if (t < 196608 + 262144) {  // ff w1 [L][128][512] -> [L][512][128]
    int u = t - 196608;
    int l = u / 65536, v = u % 65536;
    int n = v / 128, k = v % 128;
    w1T[u] = (__bf16)ffw1[l * 65536 + k * 512 + n];
  } else if (t < 458752 + 262144) {  // ff w2 [L][512][128] -> [L][128][512]
    int u = t - 458752;
    int l = u / 65536, v = u % 65536;
    int n = v / 512, k = v % 512;
    w2T[u] = (__bf16)ffw2[l * 65536 + k * 128 + n];
  } else if (t < 720896 + 65536) {  // Wo [L][128][128] -> [L][128][128]^T
    int u = t - 720896;
    int l = u / 16384, v = u % 16384;
    int n = v / 128, k = v % 128;
    woT[u] = (__bf16)Wo[l * 16384 + k * 128 + n];
  } else if (t < 786432 + 8192) {  // ec_w2 [128][64] -> [64][128]
    int u = t - 786432;
    int n = u / 128, k = u % 128;
    w2ET[u] = (__bf16)ecw2[k * 64 + n];
  } else if (t < 794624 + 8192) {
    int u = t - 794624;
    int n = u / 128, k = u % 128;
    w2PT[u] = (__bf16)ppw2[k * 64 + n];
  }
}

// ---------------- prep for final L1: fold edge_feat MLP into the weights ----------------
__global__ void k_prep(const float* __restrict__ ec_w1, const float* __restrict__ ec_b1,
                       const float* __restrict__ pp_w1, const float* __restrict__ pp_b1,
                       const float* __restrict__ ee_w2, const float* __restrict__ ee_b2,
                       __bf16* __restrict__ w1ET, __bf16* __restrict__ w1PT,
                       float* __restrict__ b1Ep, float* __restrict__ b1Pp) {
  int tid = threadIdx.x;  // 0..255
  int p = tid >> 7, n = tid & 127;
  const float* w1 = p ? pp_w1 : ec_w1;
  const float* bb = p ? pp_b1 : ec_b1;
  __bf16* wT = p ? w1PT : w1ET;
  float* bo = p ? b1Pp : b1Ep;
  for (int k = 0; k < 256; ++k) wT[n * KE1 + k] = (__bf16)w1[k * 128 + n];
  for (int i = 0; i < 32; ++i) {
    float m = 0.f;
    for (int j = 0; j < 64; ++j) m = fmaf(ee_w2[i * 64 + j], w1[(256 + j) * 128 + n], m);
    wT[n * KE1 + 256 + i] = (__bf16)m;
  }
  float b = bb[n];
  for (int j = 0; j < 64; ++j) b = fmaf(ee_b2[j], w1[(256 + j) * 128 + n], b);
  bo[n] = b;
}

// ---------- QKV layer 0: col-split, 16 nodes/block, 4 waves (wave = 6 nb of 24) ----------
__global__ __launch_bounds__(256) void k_qkv(const __bf16* __restrict__ h_bf,
                                             const __bf16* __restrict__ wT,
                                             __bf16* __restrict__ Q, __bf16* __restrict__ K,
                                             __bf16* __restrict__ V) {
  int tid = threadIdx.x, wv = tid >> 6, lane = tid & 63;
  int lr = lane & 15, lk = (lane >> 4) * 8, g4 = (lane >> 4) * 4;
  int n0 = blockIdx.x * 16;
  const __bf16* hp = h_bf + (size_t)(n0 + lr) * D;
  f32x4 acc[6];
#pragma unroll
  for (int j = 0; j < 6; ++j) acc[j] = (f32x4){0.f, 0.f, 0.f, 0.f};
#pragma unroll
  for (int ks = 0; ks < 4; ++ks) {
    bf16x8_t aF = *(const bf16x8_t*)&hp[ks * 32 + lk];
#pragma unroll
    for (int j = 0; j < 6; ++j) {
      int nb = wv * 6 + j;
      bf16x8_t bF = *(const bf16x8_t*)&wT[(nb * 16 + lr) * 128 + ks * 32 + lk];
      acc[j] = __builtin_amdgcn_mfma_f32_16x16x32_bf16(aF, bF, acc[j], 0, 0, 0);
    }
  }
#pragma unroll
  for (int j = 0; j < 6; ++j) {
    int nb = wv * 6 + j;
    int m = nb >> 3;
    __bf16* out = (m == 0) ? Q : (m == 1) ? K : V;
#pragma unroll
    for (int r = 0; r < 4; ++r)
      out[(size_t)(n0 + g4 + r) * D + (nb & 7) * 16 + lr] = (__bf16)acc[j][r];
  }
}

// ---------------- edge attention: scalar score sums per (dst, head), atomics ----------
__global__ void k_edge_attn(const int* __restrict__ src, const int* __restrict__ dst,
                            const float* __restrict__ ew, const __bf16* __restrict__ Q,
                            const __bf16* __restrict__ K, float* __restrict__ sc) {
  int t = blockIdx.x * blockDim.x + threadIdx.x;
  if (t >= N_EDGES * 8) return;
  int e = t >> 3, hd = t & 7;
  int s = src[e], d = dst[e];
  const __bf16* q = Q + (size_t)s * D + hd * 16;
  const __bf16* k = K + (size_t)d * D + hd * 16;
  bf16x8_t q0 = *(const bf16x8_t*)q, q1 = *(const bf16x8_t*)(q + 8);
  bf16x8_t k0 = *(const bf16x8_t*)k, k1 = *(const bf16x8_t*)(k + 8);
  float p = 0.f;
#pragma unroll
  for (int i = 0; i < 8; ++i) p = fmaf((float)q0[i], (float)k0[i], p);
#pragma unroll
  for (int i = 0; i < 8; ++i) p = fmaf((float)q1[i], (float)k1[i], p);
  atomicAdd(&sc[d * 8 + hd], p * SCALE * ew[e]);
}

// ---- fused node kernel, col-split: 16 nodes/block, 4 waves each owning a col slice ----
// Zeroes its sc slots after reading (saves per-layer memset). Last layer
// (wqkvT_next==nullptr): computes Ps/Pd for the final MLPs instead of QKV.
__global__ __launch_bounds__(256) void k_node(
    float* __restrict__ sc, const float* __restrict__ cnt, const __bf16* __restrict__ Vin,
    float* __restrict__ h, __bf16* __restrict__ h_bf, const __bf16* __restrict__ woT,
    const float* __restrict__ Wo_b, const float* __restrict__ ln1_s,
    const float* __restrict__ ln1_b, const __bf16* __restrict__ w1T,
    const __bf16* __restrict__ w2T, const float* __restrict__ b1,
    const float* __restrict__ b2, const float* __restrict__ ln2_s,
    const float* __restrict__ ln2_b, const __bf16* __restrict__ wqkvT_next,
    __bf16* __restrict__ Q, __bf16* __restrict__ K, __bf16* __restrict__ Vout,
    const __bf16* __restrict__ w1ET, const __bf16* __restrict__ w1PT,
    __bf16* __restrict__ PsE, __bf16* __restrict__ PdE, __bf16* __restrict__ PsP,
    __bf16* __restrict__ PdP) {
  __shared__ __bf16 z0[16][136];
  __shared__ __bf16 z1[16][520];
  __shared__ float lnb[4][16][2];
  int tid = threadIdx.x, wv = tid >> 6, lane = tid & 63;
  int lr = lane & 15, lk = (lane >> 4) * 8, g4 = (lane >> 4) * 4;
  int n0 = blockIdx.x * 16;
  int nd = n0 + lr;  // exact: 1250*16 == N_NODES

  // ---- phase 1: att-out GEMM, wave cols [wv*32, wv*32+32) ----
  float inv = 1.f / fmaxf(cnt[nd], 1.f);
  float scs[8];
#pragma unroll
  for (int i = 0; i < 8; ++i) scs[i] = sc[nd * 8 + i] * inv;
  f32x4 acc[2];
#pragma unroll
  for (int j = 0; j < 2; ++j) {
    float bv = Wo_b[(wv * 2 + j) * 16 + lr];
    acc[j] = (f32x4){bv, bv, bv, bv};
  }
#pragma unroll
  for (int ks = 0; ks < 4; ++ks) {
    bf16x8_t v8 = *(const bf16x8_t*)&Vin[(size_t)nd * D + ks * 32 + lk];
    float m = scs[(ks * 32 + lk) >> 4];
    bf16x8_t aF;
#pragma unroll
    for (int i = 0; i < 8; ++i) aF[i] = (__bf16)((float)v8[i] * m);
#pragma unroll
    for (int j = 0; j < 2; ++j) {
      bf16x8_t bF = *(const bf16x8_t*)&woT[((wv * 2 + j) * 16 + lr) * 128 + ks * 32 + lk];
      acc[j] = __builtin_amdgcn_mfma_f32_16x16x32_bf16(aF, bF, acc[j], 0, 0, 0);
    }
  }
  // residual + LN1 partials
  float y[2][4];
#pragma unroll
  for (int j = 0; j < 2; ++j)
#pragma unroll
    for (int r = 0; r < 4; ++r)
      y[j][r] = h[(size_t)(n0 + g4 + r) * D + (wv * 2 + j) * 16 + lr] + acc[j][r];
  float s_[4], q_[4];
#pragma unroll
  for (int r = 0; r < 4; ++r) {
    float a0 = y[0][r], a1 = y[1][r];
    float s = a0 + a1, q = fmaf(a0, a0, a1 * a1);
    s += __shfl_xor(s, 1); s += __shfl_xor(s, 2); s += __shfl_xor(s, 4); s += __shfl_xor(s, 8);
    q += __shfl_xor(q, 1); q += __shfl_xor(q, 2); q += __shfl_xor(q, 4); q += __shfl_xor(q, 8);
    s_[r] = s; q_[r] = q;
  }
  if (lr == 0) {
#pragma unroll
    for (int r = 0; r < 4; ++r) {
      lnb[wv][g4 + r][0] = s_[r];
      lnb[wv][g4 + r][1] = q_[r];
    }
  }
  __syncthreads();  // A: lnb1 ready; all waves past sc reads
  if (tid < 128) sc[n0 * 8 + tid] = 0.f;  // zero for next layer
  float mean[4], rstd[4];
#pragma unroll
  for (int r = 0; r < 4; ++r) {
    float sm = 0.f, sq = 0.f;
#pragma unroll
    for (int w2i = 0; w2i < 4; ++w2i) {
      sm += lnb[w2i][g4 + r][0];
      sq += lnb[w2i][g4 + r][1];
    }
    float mu = sm * (1.f / 128.f);
    mean[r] = mu;
    rstd[r] = rsqrtf(sq * (1.f / 128.f) - mu * mu + 1e-5f);
  }
#pragma unroll
  for (int j = 0; j < 2; ++j) {
    int col = (wv * 2 + j) * 16 + lr;
    float lsv = ln1_s[col], lbv = ln1_b[col];
#pragma unroll
    for (int r = 0; r < 4; ++r) {
      y[j][r] = (y[j][r] - mean[r]) * rstd[r] * lsv + lbv;
      z0[g4 + r][col] = (__bf16)y[j][r];
    }
  }
  __syncthreads();  // B: z0 ready

  // ---- FF1: wave cols [wv*128, wv*128+128) of 512 ----
  f32x4 a1[8];
#pragma unroll
  for (int j = 0; j < 8; ++j) {
    float bv = b1[(wv * 8 + j) * 16 + lr];
    a1[j] = (f32x4){bv, bv, bv, bv};
  }
#pragma unroll
  for (int ks = 0; ks < 4; ++ks) {
    bf16x8_t aF = *(const bf16x8_t*)&z0[lr][ks * 32 + lk];
#pragma unroll
    for (int j = 0; j < 8; ++j) {
      bf16x8_t bF = *(const bf16x8_t*)&w1T[((wv * 8 + j) * 16 + lr) * 128 + ks * 32 + lk];
      a1[j] = __builtin_amdgcn_mfma_f32_16x16x32_bf16(aF, bF, a1[j], 0, 0, 0);
    }
  }
#pragma unroll
  for (int j = 0; j < 8; ++j)
#pragma unroll
    for (int r = 0; r < 4; ++r)
      z1[g4 + r][(wv * 8 + j) * 16 + lr] = (__bf16)fmaxf(a1[j][r], 0.f);
  __syncthreads();  // C: z1 ready, z0 free

  // ---- FF2: wave cols [wv*32, wv*32+32), k = 512 ----
  f32x4 a2[2];
#pragma unroll
  for (int j = 0; j < 2; ++j) {
    float bv = b2[(wv * 2 + j) * 16 + lr];
    a2[j] = (f32x4){bv, bv, bv, bv};
  }
#pragma unroll
  for (int ks = 0; ks < 16; ++ks) {
    bf16x8_t aF = *(const bf16x8_t*)&z1[lr][ks * 32 + lk];
#pragma unroll
    for (int j = 0; j < 2; ++j) {
      bf16x8_t bF = *(const bf16x8_t*)&w2T[((wv * 2 + j) * 16 + lr) * 512 + ks * 32 + lk];
      a2[j] = __builtin_amdgcn_mfma_f32_16x16x32_bf16(aF, bF, a2[j], 0, 0, 0);
    }
  }
  // residual (post-LN1 y) + LN2
#pragma unroll
  for (int j = 0; j < 2; ++j)
#pragma unroll
    for (int r = 0; r < 4; ++r) y[j][r] += a2[j][r];
#pragma unroll
  for (int r = 0; r < 4; ++r) {
    float a0 = y[0][r], a1v = y[1][r];
    float s = a0 + a1v, q = fmaf(a0, a0, a1v * a1v);
    s += __shfl_xor(s, 1); s += __shfl_xor(s, 2); s += __shfl_xor(s, 4); s += __shfl_xor(s, 8);
    q += __shfl_xor(q, 1); q += __shfl_xor(q, 2); q += __shfl_xor(q, 4); q += __shfl_xor(q, 8);
    s_[r] = s; q_[r] = q;
  }
  if (lr == 0) {
#pragma unroll
    for (int r = 0; r < 4; ++r) {
      lnb[wv][g4 + r][0] = s_[r];
      lnb[wv][g4 + r][1] = q_[r];
    }
  }
  __syncthreads();  // D: lnb2 ready
#pragma unroll
  for (int r = 0; r < 4; ++r) {
    float sm = 0.f, sq = 0.f;
#pragma unroll
    for (int w2i = 0; w2i < 4; ++w2i) {
      sm += lnb[w2i][g4 + r][0];
      sq += lnb[w2i][g4 + r][1];
    }
    float mu = sm * (1.f / 128.f);
    mean[r] = mu;
    rstd[r] = rsqrtf(sq * (1.f / 128.f) - mu * mu + 1e-5f);
  }
#pragma unroll
  for (int j = 0; j < 2; ++j) {
    int col = (wv * 2 + j) * 16 + lr;
    float lsv = ln2_s[col], lbv = ln2_b[col];
#pragma unroll
    for (int r = 0; r < 4; ++r) {
      float yv = (y[j][r] - mean[r]) * rstd[r] * lsv + lbv;
      y[j][r] = yv;
      h[(size_t)(n0 + g4 + r) * D + col] = yv;
      h_bf[(size_t)(n0 + g4 + r) * D + col] = (__bf16)yv;
    }
  }

  // ---- restage y2 into z0 for the tail GEMM (QKV or final-P) ----
#pragma unroll
  for (int j = 0; j < 2; ++j)
#pragma unroll
    for (int r = 0; r < 4; ++r)
      z0[g4 + r][(wv * 2 + j) * 16 + lr] = (__bf16)y[j][r];
  __syncthreads();  // E: z0 = y2 ready

  if (wqkvT_next) {
    // ---- next-layer QKV, col-split 6 nb/wave ----
    f32x4 aq[6];
#pragma unroll
    for (int j = 0; j < 6; ++j) aq[j] = (f32x4){0.f, 0.f, 0.f, 0.f};
#pragma unroll
    for (int ks = 0; ks < 4; ++ks) {
      bf16x8_t aF = *(const bf16x8_t*)&z0[lr][ks * 32 + lk];
#pragma unroll
      for (int j = 0; j < 6; ++j) {
        int nb = wv * 6 + j;
        bf16x8_t bF = *(const bf16x8_t*)&wqkvT_next[(nb * 16 + lr) * 128 + ks * 32 + lk];
        aq[j] = __builtin_amdgcn_mfma_f32_16x16x32_bf16(aF, bF, aq[j], 0, 0, 0);
      }
    }
#pragma unroll
    for (int j = 0; j < 6; ++j) {
      int nb = wv * 6 + j;
      int m = nb >> 3;
      __bf16* out = (m == 0) ? Q : (m == 1) ? K : Vout;
#pragma unroll
      for (int r = 0; r < 4; ++r)
        out[(size_t)(n0 + g4 + r) * D + (nb & 7) * 16 + lr] = (__bf16)aq[j][r];
    }
  } else {
    // ---- final-P: wave wv -> {PsE, PdE, PsP, PdP}, own 16 rows (safe: Vin reads done) ----
    const __bf16* wsrc = (wv & 2) ? w1PT : w1ET;
    int koff = (wv & 1) ? 128 : 0;
    __bf16* outP = (wv == 0) ? PsE : (wv == 1) ? PdE : (wv == 2) ? PsP : PdP;
    f32x4 ap[8];
#pragma unroll
    for (int nb = 0; nb < 8; ++nb) ap[nb] = (f32x4){0.f, 0.f, 0.f, 0.f};
#pragma unroll
    for (int ks = 0; ks < 4; ++ks) {
      bf16x8_t aF = *(const bf16x8_t*)&z0[lr][ks * 32 + lk];
#pragma unroll
      for (int nb = 0; nb < 8; ++nb) {
        bf16x8_t bF = *(const bf16x8_t*)&wsrc[(nb * 16 + lr) * KE1 + koff + ks * 32 + lk];
        ap[nb] = __builtin_amdgcn_mfma_f32_16x16x32_bf16(aF, bF, ap[nb], 0, 0, 0);
      }
    }
#pragma unroll
    for (int nb = 0; nb < 8; ++nb)
#pragma unroll
      for (int r = 0; r < 4; ++r)
        outP[(size_t)(n0 + g4 + r) * D + nb * 16 + lr] = (__bf16)ap[nb][r];
  }
}

// ---------------- final edge MLPs: L1 hoisted to nodes; zf aliased into z1 ----------
// 256 threads = 4 waves: wave = {path p = wv&1, tile t = wv>>1}. 32 edges/block.
// LDS = 17.4 KB (zf lives in z1's own region, in-place relu(Ps+Pd+zf)).
__global__ __launch_bounds__(256) void k_final(
    const int* __restrict__ src, const int* __restrict__ dst, const float* __restrict__ ea,
    const float* __restrict__ ee_w1, const float* __restrict__ ee_b1,
    const __bf16* __restrict__ w1ET, const __bf16* __restrict__ w1PT,
    const __bf16* __restrict__ w2ET, const __bf16* __restrict__ w2PT,
    const float* __restrict__ b1Ep, const float* __restrict__ b1Pp,
    const __bf16* __restrict__ PsE, const __bf16* __restrict__ PdE,
    const __bf16* __restrict__ PsP, const __bf16* __restrict__ PdP,
    const float* __restrict__ ec_b2, const float* __restrict__ ec_w3,
    const float* __restrict__ ec_b3, const float* __restrict__ pp_b2,
    const float* __restrict__ pp_w3, const float* __restrict__ pp_b3,
    float* __restrict__ out_logits, float* __restrict__ out_params) {
  __shared__ __bf16 z1[2][32][136];
  int tid = threadIdx.x, wv = tid >> 6, lane = tid & 63;
  int lr = lane & 15, lk = (lane >> 4) * 8, g4 = (lane >> 4) * 4;
  int p = wv & 1, m0 = (wv >> 1) * 16;
  int e0 = blockIdx.x * 32;
  int e = e0 + m0 + lr;
  float av = ea[e];
  bf16x8_t aR;
#pragma unroll
  for (int i = 0; i < 8; ++i)
    aR[i] = (__bf16)fmaxf(fmaf(av, ee_w1[lk + i], ee_b1[lk + i]), 0.f);

  const __bf16* w1x = p ? w1PT : w1ET;
  const float* b1x = p ? b1Pp : b1Ep;
  const __bf16* w2x = p ? w2PT : w2ET;
  const float* b2x = p ? pp_b2 : ec_b2;

  // ---- feat part of L1: K=32 MFMA (bias-initialized) -> staged into z1's own region ----
  f32x4 acc[8];
#pragma unroll
  for (int nb = 0; nb < 8; ++nb) {
    float bv = b1x[nb * 16 + lr];
    acc[nb] = (f32x4){bv, bv, bv, bv};
  }
#pragma unroll
  for (int nb = 0; nb < 8; ++nb) {
    bf16x8_t bF = *(const bf16x8_t*)&w1x[(nb * 16 + lr) * KE1 + 256 + lk];
    acc[nb] = __builtin_amdgcn_mfma_f32_16x16x32_bf16(aR, bF, acc[nb], 0, 0, 0);
  }
#pragma unroll
  for (int nb = 0; nb < 8; ++nb)
#pragma unroll
    for (int r = 0; r < 4; ++r) z1[p][m0 + g4 + r][nb * 16 + lr] = (__bf16)acc[nb][r];

  // ---- z1 assembly in place: lane = em*4 + c4; z1 = relu(Ps[src] + Pd[dst] + z1) ----
  // Each (row, 32-col chunk) address is read+written by exactly one lane; LDS ops are
  // in-order within a wave -> no barrier needed.
  {
    int em = lane >> 2, c4 = lane & 3;
    int ee = e0 + m0 + em;
    const __bf16* Ps = p ? PsP : PsE;
    const __bf16* Pd = p ? PdP : PdE;
    const __bf16* psrow = Ps + (size_t)src[ee] * D + c4 * 32;
    const __bf16* pdrow = Pd + (size_t)dst[ee] * D + c4 * 32;
#pragma unroll
    for (int ch = 0; ch < 4; ++ch) {
      bf16x8_t a = *(const bf16x8_t*)&psrow[ch * 8];
      bf16x8_t b = *(const bf16x8_t*)&pdrow[ch * 8];
      bf16x8_t f = *(const bf16x8_t*)&z1[p][m0 + em][c4 * 32 + ch * 8];
      bf16x8_t o;
#pragma unroll
      for (int i = 0; i < 8; ++i)
        o[i] = (__bf16)fmaxf((float)a[i] + (float)b[i] + (float)f[i], 0.f);
      *(bf16x8_t*)&z1[p][m0 + em][c4 * 32 + ch * 8] = o;
    }
  }
  // wave-local rows -> no barrier anywhere

  // ---- layer 2: k=128, 64 cols ----
  f32x4 acc2[4];
#pragma unroll
  for (int nb = 0; nb < 4; ++nb) {
    float bv = b2x[nb * 16 + lr];
    acc2[nb] = (f32x4){bv, bv, bv, bv};
  }
#pragma unroll
  for (int ks = 0; ks < 4; ++ks) {
    bf16x8_t aF = *(const bf16x8_t*)&z1[p][m0 + lr][ks * 32 + lk];
#pragma unroll
    for (int nb = 0; nb < 4; ++nb) {
      bf16x8_t bF = *(const bf16x8_t*)&w2x[(nb * 16 + lr) * 128 + ks * 32 + lk];
      acc2[nb] = __builtin_amdgcn_mfma_f32_16x16x32_bf16(aF, bF, acc2[nb], 0, 0, 0);
    }
  }

  // ---- layer 3 ----
  if (p == 0) {
    float w3v[4];
#pragma unroll
    for (int nb = 0; nb < 4; ++nb) w3v[nb] = ec_w3[nb * 16 + lr];
    float b3 = ec_b3[0];
#pragma unroll
    for (int r = 0; r < 4; ++r) {
      float s = 0.f;
#pragma unroll
      for (int nb = 0; nb < 4; ++nb) s = fmaf(fmaxf(acc2[nb][r], 0.f), w3v[nb], s);
      s += __shfl_xor(s, 1);
      s += __shfl_xor(s, 2);
      s += __shfl_xor(s, 4);
      s += __shfl_xor(s, 8);
      if (lr == 0) out_logits[e0 + m0 + g4 + r] = s + b3;
    }
  } else {
    float wp[4][4];
#pragma unroll
    for (int nb = 0; nb < 4; ++nb)
#pragma unroll
      for (int c = 0; c < 4; ++c) wp[nb][c] = pp_w3[(nb * 16 + lr) * 4 + c];
#pragma unroll
    for (int c = 0; c < 4; ++c) {
      float b3 = pp_b3[c];
#pragma unroll
      for (int r = 0; r < 4; ++r) {
        float s = 0.f;
#pragma unroll
        for (int nb = 0; nb < 4; ++nb) s = fmaf(fmaxf(acc2[nb][r], 0.f), wp[nb][c], s);
        s += __shfl_xor(s, 1);
        s += __shfl_xor(s, 2);
        s += __shfl_xor(s, 4);
        s += __shfl_xor(s, 8);
        if (lr == 0) {
          float xx = s + b3;
          float sp = fmaxf(xx, 0.f) + log1pf(expf(-fabsf(xx)));
          out_params[(size_t)(e0 + m0 + g4 + r) * 4 + c] = sp + 1e-6f;
        }
      }
    }
  }
}

extern "C" void kernel_launch(void* const* d_in, const int* in_sizes, int n_in,
                              void* d_out, int out_size, void* d_ws, size_t ws_size,
                              hipStream_t stream) {
  const float* x = (const float*)d_in[0];
  const int* eidx = (const int*)d_in[1];
  const float* eattr = (const float*)d_in[2];
  const float* in_w = (const float*)d_in[3];
  const float* in_b = (const float*)d_in[4];
  const float* ee_w1 = (const float*)d_in[5];
  const float* ee_b1 = (const float*)d_in[6];
  const float* ee_w2 = (const float*)d_in[7];
  const float* ee_b2 = (const float*)d_in[8];
  const float* Wq = (const float*)d_in[9];
  const float* Wk = (const float*)d_in[10];
  const float* Wv = (const float*)d_in[11];
  const float* Wo = (const float*)d_in[12];
  const float* Wo_b = (const float*)d_in[13];
  const float* ff_w1 = (const float*)d_in[14];
  const float* ff_b1 = (const float*)d_in[15];
  const float* ff_w2 = (const float*)d_in[16];
  const float* ff_b2 = (const float*)d_in[17];
  const float* ln1_s = (const float*)d_in[18];
  const float* ln1_b = (const float*)d_in[19];
  const float* ln2_s = (const float*)d_in[20];
  const float* ln2_b = (const float*)d_in[21];
  const float* ec_w1 = (const float*)d_in[22];
  const float* ec_b1 = (const float*)d_in[23];
  const float* ec_w2 = (const float*)d_in[24];
  const float* ec_b2 = (const float*)d_in[25];
  const float* ec_w3 = (const float*)d_in[26];
  const float* ec_b3 = (const float*)d_in[27];
  const float* pp_w1 = (const float*)d_in[28];
  const float* pp_b1 = (const float*)d_in[29];
  const float* pp_w2 = (const float*)d_in[30];
  const float* pp_b2 = (const float*)d_in[31];
  const float* pp_w3 = (const float*)d_in[32];
  const float* pp_b3 = (const float*)d_in[33];

  const int* src = eidx;
  const int* dst = eidx + N_EDGES;

  // Workspace layout (39.6 MB, 16B-aligned)
  char* wsb = (char*)d_ws;
  float* sc = (float*)wsb;                     //    640,000
  float* cnt = (float*)(wsb + 640000);         //     80,000
  float* h = (float*)(wsb + 720000);           // 10,240,000
  __bf16* h_bf = (__bf16*)(wsb + 10960000);    //  5,120,000
  __bf16* Q = (__bf16*)(wsb + 16080000);       //  5,120,000
  __bf16* Kb = (__bf16*)(wsb + 21200000);      //  5,120,000
  __bf16* V0 = (__bf16*)(wsb + 26320000);      //  5,120,000
  __bf16* V1 = (__bf16*)(wsb + 31440000);      //  5,120,000
  float* ew = (float*)(wsb + 36560000);        //  1,280,000
  __bf16* wqkvT = (__bf16*)(wsb + 37840000);   //    393,216
  __bf16* w1T = (__bf16*)(wsb + 38233216);     //    524,288
  __bf16* w2T = (__bf16*)(wsb + 38757504);     //    524,288
  __bf16* woT = (__bf16*)(wsb + 39281792);     //    131,072
  __bf16* w1ET = (__bf16*)(wsb + 39412864);    //     73,728
  __bf16* w1PT = (__bf16*)(wsb + 39486592);    //     73,728
  __bf16* w2ET = (__bf16*)(wsb + 39560320);    //     16,384
  __bf16* w2PT = (__bf16*)(wsb + 39576704);    //     16,384
  float* b1Ep = (float*)(wsb + 39593088);      //        512
  float* b1Pp = (float*)(wsb + 39593600);      //        512 -> 39,594,112

  hipMemsetAsync(cnt, 0, N_NODES * sizeof(float), stream);
  hipMemsetAsync(sc, 0, N_NODES * 8 * sizeof(float), stream);
  k_input_proj<<<N_NODES, D, 0, stream>>>(x, in_w, in_b, h, h_bf);
  k_edge_prep<<<(N_EDGES + 255) / 256, 256, 0, stream>>>(eattr, ee_w1, ee_b1, ee_w2, ee_b2,
                                                         dst, ew, cnt);
  k_cvt_all<<<(802816 + 255) / 256, 256, 0, stream>>>(Wq, Wk, Wv, ff_w1, ff_w2, Wo, ec_w2,
                                                      pp_w2, wqkvT, w1T, w2T, woT, w2ET, w2PT);
  k_prep<<<1, 256, 0, stream>>>(ec_w1, ec_b1, pp_w1, pp_b1, ee_w2, ee_b2, w1ET, w1PT, b1Ep,
                                b1Pp);

  // Q/Kb/V0/V1 double duty: attention buffers during layers; Ps/Pd after the last k_node.
  __bf16* PsE = Q;
  __bf16* PdE = Kb;
  __bf16* PsP = V0;
  __bf16* PdP = V1;

  int nblk = N_NODES / 16;  // 1250, exact
  k_qkv<<<nblk, 256, 0, stream>>>(h_bf, wqkvT, Q, Kb, V0);
  for (int l = 0; l < NLAYER; ++l) {
    __bf16* Vin = (l & 1) ? V1 : V0;
    __bf16* Vout = (l & 1) ? V0 : V1;
    k_edge_attn<<<(N_EDGES * 8 + 255) / 256, 256, 0, stream>>>(src, dst, ew, Q, Kb, sc);
    k_node<<<nblk, 256, 0, stream>>>(
        sc, cnt, Vin, h, h_bf, woT + (size_t)l * 16384, Wo_b + l * D, ln1_s + l * D,
        ln1_b + l * D, w1T + (size_t)l * 65536, w2T + (size_t)l * 65536, ff_b1 + l * DFF,
        ff_b2 + l * D, ln2_s + l * D, ln2_b + l * D,
        (l < NLAYER - 1) ? (wqkvT + (size_t)(l + 1) * 49152) : (const __bf16*)nullptr, Q, Kb,
        Vout, w1ET, w1PT, PsE, PdE, PsP, PdP);
  }

  float* out_logits = (float*)d_out;
  float* out_params = out_logits + N_EDGES;
  k_final<<<N_EDGES / 32, 256, 0, stream>>>(src, dst, eattr, ee_w1, ee_b1, w1ET, w1PT, w2ET,
                                            w2PT, b1Ep, b1Pp, PsE, PdE, PsP, PdP, ec_b2,
                                            ec_w3, ec_b3, pp_b2, pp_w3, pp_b3, out_logits,
                                            out_params);
}